// Round 5
// baseline (880.229 us; speedup 1.0000x reference)
//
#include <hip/hip_runtime.h>
#include <math.h>

#define B 256
#define N 128
#define E 2048
#define D 512
#define R 1024
#define O 10
#define L 5
#define BK 32

typedef unsigned short u16;
typedef unsigned int u32;
typedef __bf16 bf16x8 __attribute__((ext_vector_type(8)));
typedef u16 u16x8 __attribute__((ext_vector_type(8)));
typedef float floatx4 __attribute__((ext_vector_type(4)));

// Packed h layout ("A-fragment order"):
//   element h[b][n][k]  ->  flat (((b*8 + (n>>4))*16 + (k>>5))*64 + lane)*8 + (k&7)
//   with lane = (n&15) + 16*((k>>3)&3).
// A wave reads one 16n x 32k fragment as ONE coalesced 1KB global_load_dwordx4.

// ---- bf16 helpers (RNE) ----------------------------------------------------
__device__ inline u16 f2bf(float f) {
    union { float f; u32 u; } v; v.f = f;
    u32 u = v.u;
    return (u16)((u + 0x7fffu + ((u >> 16) & 1u)) >> 16);
}
__device__ inline float bf2f(u16 s) {
    union { u32 u; float f; } v; v.u = ((u32)s) << 16;
    return v.f;
}

__device__ inline float fast_tanh(float x) {
    return 1.0f - 2.0f / (__expf(2.0f * x) + 1.0f);
}

// ---- async global->LDS, 16B per lane ---------------------------------------
__device__ inline void gload16(const void* g, void* l) {
    __builtin_amdgcn_global_load_lds(
        (const __attribute__((address_space(1))) void*)g,
        (__attribute__((address_space(3))) void*)l, 16, 0, 0);
}

__device__ inline bf16x8 ldsfrag(const u16* p) {
    u16x8 v = *(const u16x8*)p;
    return __builtin_bit_cast(bf16x8, v);
}
__device__ inline bf16x8 gfrag(const u16* p) {
    uint4 v = *(const uint4*)p;
    return __builtin_bit_cast(bf16x8, v);
}

// ---------------------------------------------------------------------------
__global__ void zero_kernel(float* __restrict__ p, size_t n) {
    size_t i = (size_t)blockIdx.x * blockDim.x + threadIdx.x;
    size_t stride = (size_t)gridDim.x * blockDim.x;
    for (; i < n; i += stride) p[i] = 0.f;
}

__global__ void fill_adj_kernel(const int* __restrict__ edges, float* __restrict__ C) {
    int idx = blockIdx.x * blockDim.x + threadIdx.x;
    if (idx >= B * E) return;
    int b = idx / E;
    int e = idx - b * E;
    int src = edges[b * 2 * E + e];
    int dst = edges[b * 2 * E + E + e];
    atomicAdd(&C[(size_t)b * N * N + (size_t)dst * N + src], 1.0f);
}

__global__ void diag_kernel(float* __restrict__ C) {
    int idx = blockIdx.x * blockDim.x + threadIdx.x;
    if (idx >= B * N) return;
    C[(size_t)(idx >> 7) * N * N + (size_t)(idx & 127) * 129] += 1.0f;
}

__global__ void cbf_kernel(const float4* __restrict__ C4, ushort4* __restrict__ o, size_t n4) {
    size_t i = (size_t)blockIdx.x * blockDim.x + threadIdx.x;
    size_t stride = (size_t)gridDim.x * blockDim.x;
    for (; i < n4; i += stride) {
        float4 v = C4[i];
        ushort4 r;
        r.x = f2bf(v.x); r.y = f2bf(v.y); r.z = f2bf(v.z); r.w = f2bf(v.w);
        o[i] = r;
    }
}

// ---------------------------------------------------------------------------
// split x (fp32) -> hi/lo bf16 pair in PACKED layout
// ---------------------------------------------------------------------------
__global__ void split_kernel(const float4* __restrict__ x4,
                             u16* __restrict__ hp_hi, u16* __restrict__ hp_lo, size_t n4) {
    size_t i = (size_t)blockIdx.x * blockDim.x + threadIdx.x;
    size_t stride = (size_t)gridDim.x * blockDim.x;
    for (; i < n4; i += stride) {
        float4 v = x4[i];
        const int d0 = ((int)(i & 127)) * 4;          // D/4 = 128
        const int n  = (int)((i >> 7) & 127);
        const int bb = (int)(i >> 14);
        u16 h0 = f2bf(v.x), h1 = f2bf(v.y), h2 = f2bf(v.z), h3 = f2bf(v.w);
        uint2 hp; hp.x = (u32)h0 | ((u32)h1 << 16); hp.y = (u32)h2 | ((u32)h3 << 16);
        u16 l0 = f2bf(v.x - bf2f(h0)), l1 = f2bf(v.y - bf2f(h1));
        u16 l2 = f2bf(v.z - bf2f(h2)), l3 = f2bf(v.w - bf2f(h3));
        uint2 lp; lp.x = (u32)l0 | ((u32)l1 << 16); lp.y = (u32)l2 | ((u32)l3 << 16);
        const int lane_p = (n & 15) + 16 * ((d0 >> 3) & 3);
        size_t e = ((((size_t)bb * 8 + (n >> 4)) * 16 + (d0 >> 5)) * 64 + lane_p) * 8 + (d0 & 7);
        *(uint2*)(hp_hi + e) = hp;
        *(uint2*)(hp_lo + e) = lp;
    }
}

// ---------------------------------------------------------------------------
// transpose+split W_cp[l][0:512][1024] fp32 -> Wt_hi/Wt_lo [l][1024 r][512 k]
// ---------------------------------------------------------------------------
__global__ __launch_bounds__(256)
void wt_split_kernel(const float* __restrict__ W_cp,
                     u16* __restrict__ Wt_hi, u16* __restrict__ Wt_lo) {
    __shared__ float t[64][65];
    const int l = blockIdx.z, k0 = blockIdx.y * 64, r0 = blockIdx.x * 64;
    const float* Wl = W_cp + (size_t)l * 513 * 1024;
    const int tx = threadIdx.x & 63, ty = threadIdx.x >> 6;
#pragma unroll
    for (int p = 0; p < 16; ++p) {
        int k = ty + p * 4;
        t[k][tx] = Wl[(size_t)(k0 + k) * 1024 + r0 + tx];
    }
    __syncthreads();
    u16* oh = Wt_hi + ((size_t)l * 1024 + r0) * 512 + k0;
    u16* ol = Wt_lo + ((size_t)l * 1024 + r0) * 512 + k0;
#pragma unroll
    for (int p = 0; p < 16; ++p) {
        int r = ty + p * 4;
        float v = t[tx][r];
        u16 hv = f2bf(v);
        oh[(size_t)r * 512 + tx] = hv;
        ol[(size_t)r * 512 + tx] = f2bf(v - bf2f(hv));
    }
}

// ---------------------------------------------------------------------------
// cp_pool, A-direct version: A-frags (packed h) stream global->VGPR double-
// buffered; only W goes through LDS. Per step: B1 -> ds_read B-frags -> B2 ->
// issue next B-stage + next A-frag loads -> 48-MFMA burst.
// ---------------------------------------------------------------------------
__global__ __launch_bounds__(256)
void cp_pool_mfma_kernel(const u16* __restrict__ hp_hi, const u16* __restrict__ hp_lo,
                         const u16* __restrict__ Wt_hi, const u16* __restrict__ Wt_lo,
                         const float* __restrict__ Wbias,   // [1024] fp32 (W row 512)
                         float* __restrict__ prod_out)      // [B][R] this layer
{
    __shared__ u16 Bs_hi[128 * BK], Bs_lo[128 * BK];
    __shared__ float red[2][128];

    const int flat = blockIdx.x;
    const int s    = flat >> 3;
    const int b    = (flat & 7) * 32 + (s >> 3);
    const int r0   = (s & 7) * 128;

    const int tid  = threadIdx.x;
    const int w    = tid >> 6;
    const int lane = tid & 63;
    const int rb   = w & 1;
    const int cb   = w >> 1;

    floatx4 acc[4][4];
#pragma unroll
    for (int i = 0; i < 4; ++i)
#pragma unroll
        for (int j = 0; j < 4; ++j)
#pragma unroll
            for (int k = 0; k < 4; ++k) acc[i][j][k] = 0.f;

    // W staging (unchanged xor-swizzle path)
    const int srow = w * 32 + (lane >> 2);
    const int kswz = (((lane & 3) ^ ((lane >> 3) & 3)) * 8);
    const u16* gBh = Wt_hi + (size_t)(r0 + srow) * 512 + kswz;
    const u16* gBl = Wt_lo + (size_t)(r0 + srow) * 512 + kswz;

    // A packed base: frag (t, ks) at baseA + t*8192 + ks*512
    const size_t baseA = (size_t)(b * 8 + rb * 4) * 8192 + lane * 8;

    const int bn = cb * 64 + (lane & 15);
    const int ko = (((lane >> 4) ^ ((lane >> 1) & 3)) * 8);

    bf16x8 a_hi[2][4], a_lo[2][4];

    // prologue: stage B0, load A0
#pragma unroll
    for (int it = 0; it < 2; ++it) {
        gload16(gBh + (size_t)it * 16 * 512, Bs_hi + (w * 2 + it) * 512);
        gload16(gBl + (size_t)it * 16 * 512, Bs_lo + (w * 2 + it) * 512);
    }
    gBh += BK; gBl += BK;
#pragma unroll
    for (int t = 0; t < 4; ++t) {
        a_hi[0][t] = gfrag(hp_hi + baseA + t * 8192);
        a_lo[0][t] = gfrag(hp_lo + baseA + t * 8192);
    }

    auto step = [&](int ks, int p) {
        __syncthreads();   // B1: this step's W stage complete
        bf16x8 bh[4], bl[4];
#pragma unroll
        for (int t = 0; t < 4; ++t) {
            bh[t] = ldsfrag(&Bs_hi[(bn + t * 16) * BK + ko]);
            bl[t] = ldsfrag(&Bs_lo[(bn + t * 16) * BK + ko]);
        }
        __syncthreads();   // B2: Bs buffers free
        if (ks < 15) {
#pragma unroll
            for (int it = 0; it < 2; ++it) {
                gload16(gBh + (size_t)it * 16 * 512, Bs_hi + (w * 2 + it) * 512);
                gload16(gBl + (size_t)it * 16 * 512, Bs_lo + (w * 2 + it) * 512);
            }
            gBh += BK; gBl += BK;
            const size_t off = baseA + (size_t)(ks + 1) * 512;
#pragma unroll
            for (int t = 0; t < 4; ++t) {
                a_hi[1 - p][t] = gfrag(hp_hi + off + t * 8192);
                a_lo[1 - p][t] = gfrag(hp_lo + off + t * 8192);
            }
        }
#pragma unroll
        for (int i = 0; i < 4; ++i)
#pragma unroll
            for (int j = 0; j < 4; ++j) {
                acc[i][j] = __builtin_amdgcn_mfma_f32_16x16x32_bf16(a_lo[p][i], bh[j], acc[i][j], 0, 0, 0);
                acc[i][j] = __builtin_amdgcn_mfma_f32_16x16x32_bf16(a_hi[p][i], bl[j], acc[i][j], 0, 0, 0);
                acc[i][j] = __builtin_amdgcn_mfma_f32_16x16x32_bf16(a_hi[p][i], bh[j], acc[i][j], 0, 0, 0);
            }
    };
    for (int ks = 0; ks < 16; ks += 2) { step(ks, 0); step(ks + 1, 1); }

    // epilogue: +bias, tanh, product over n
    const int quad = lane >> 4;
    const int c16  = lane & 15;
#pragma unroll
    for (int tj = 0; tj < 4; ++tj) {
        const int c = cb * 64 + tj * 16 + c16;
        const float bias = Wbias[r0 + c];
        float p = 1.f;
#pragma unroll
        for (int ti = 0; ti < 4; ++ti)
#pragma unroll
            for (int ri = 0; ri < 4; ++ri)
                p *= fast_tanh(acc[ti][tj][ri] + bias);
        p *= __shfl_xor(p, 16, 64);
        p *= __shfl_xor(p, 32, 64);
        if (quad == 0) red[rb][c] = p;
    }
    __syncthreads();
    if (tid < 128)
        prod_out[(size_t)b * R + r0 + tid] = red[0][tid] * red[1][tid];
}

// ---------------------------------------------------------------------------
// aggregate via MFMA on PACKED h: h_out = (C+I) @ h.
// A = C' (bf16) via gload16; B = h staged transposed [d][s] in LDS (reads are
// 2x uint4 from packed layout); epilogue writes packed hi/lo.
// ---------------------------------------------------------------------------
__global__ __launch_bounds__(256)
void aggregate_mfma_kernel(const u16* __restrict__ hp_hi, const u16* __restrict__ hp_lo,
                           const u16* __restrict__ Cbf,    // [B][128][128] bf16 (C+I)
                           u16* __restrict__ ho_hi, u16* __restrict__ ho_lo)
{
    __shared__ u16 Cs[128 * 32];
    __shared__ u16 Bs_hi[128 * 40];       // [d][s-chunk32], stride 40
    __shared__ u16 Bs_lo[128 * 40];

    const int flat = blockIdx.x;
    const int rest = flat >> 3;
    const int b    = (flat & 7) * 32 + (rest >> 2);
    const int d0   = (rest & 3) * 128;

    const int tid  = threadIdx.x;
    const int w    = tid >> 6;
    const int lane = tid & 63;
    const int rb   = w & 1;
    const int cb   = w >> 1;

    floatx4 acc[4][4];
#pragma unroll
    for (int i = 0; i < 4; ++i)
#pragma unroll
        for (int j = 0; j < 4; ++j)
#pragma unroll
            for (int k = 0; k < 4; ++k) acc[i][j][k] = 0.f;

    const int kswz = (((lane & 3) ^ ((lane >> 3) & 3)) * 8);
    const u16* gC = Cbf + ((size_t)b * 128 + (w * 32 + (lane >> 2))) * 128 + kswz;

    // B transpose staging from packed layout
    const int ssi = tid >> 3;           // 0..31 (s within chunk)
    const int dg  = (tid & 7) * 16;     // 0..112
    const int dA  = d0 + dg;

    const int am  = rb * 64 + (lane & 15);
    const int ko  = (((lane >> 4) ^ ((lane >> 1) & 3)) * 8);
    const int bko = (lane >> 4) * 8;

    for (int s0 = 0; s0 < 128; s0 += 32) {
#pragma unroll
        for (int it = 0; it < 2; ++it)
            gload16(gC + s0 + (size_t)it * 16 * 128, Cs + (w * 2 + it) * 512);

        {
            const int sg = s0 + ssi;
            // seg0: d = dA..dA+7 ; seg1: d = dA+8..dA+15 (lane_p + 16)
            size_t e0 = ((((size_t)b * 8 + (sg >> 4)) * 16 + (dA >> 5)) * 64
                         + ((sg & 15) + 16 * ((dA >> 3) & 3))) * 8;
            uint4 a0 = *(const uint4*)(hp_hi + e0);
            uint4 a1 = *(const uint4*)(hp_hi + e0 + 128);
            uint4 b0 = *(const uint4*)(hp_lo + e0);
            uint4 b1 = *(const uint4*)(hp_lo + e0 + 128);
            const u16* av0 = (const u16*)&a0; const u16* av1 = (const u16*)&a1;
            const u16* bv0 = (const u16*)&b0; const u16* bv1 = (const u16*)&b1;
#pragma unroll
            for (int i = 0; i < 8; ++i) {
                Bs_hi[(dg + i) * 40 + ssi]     = av0[i];
                Bs_hi[(dg + 8 + i) * 40 + ssi] = av1[i];
                Bs_lo[(dg + i) * 40 + ssi]     = bv0[i];
                Bs_lo[(dg + 8 + i) * 40 + ssi] = bv1[i];
            }
        }
        __syncthreads();

        bf16x8 af[4], bhf[4], blf[4];
#pragma unroll
        for (int t = 0; t < 4; ++t) {
            af[t]  = ldsfrag(&Cs[(am + t * 16) * 32 + ko]);
            const int d = cb * 64 + t * 16 + (lane & 15);
            bhf[t] = ldsfrag(&Bs_hi[d * 40 + bko]);
            blf[t] = ldsfrag(&Bs_lo[d * 40 + bko]);
        }
#pragma unroll
        for (int i = 0; i < 4; ++i)
#pragma unroll
            for (int j = 0; j < 4; ++j) {
                acc[i][j] = __builtin_amdgcn_mfma_f32_16x16x32_bf16(af[i], bhf[j], acc[i][j], 0, 0, 0);
                acc[i][j] = __builtin_amdgcn_mfma_f32_16x16x32_bf16(af[i], blf[j], acc[i][j], 0, 0, 0);
            }
        __syncthreads();
    }

    // epilogue: split to hi/lo, store in PACKED layout
    const int quad = lane >> 4;
    const int c16  = lane & 15;
#pragma unroll
    for (int i = 0; i < 4; ++i)
#pragma unroll
        for (int j = 0; j < 4; ++j) {
            const int D0 = d0 + cb * 64 + j * 16;        // 16-aligned
            const int kc = D0 >> 5;
            const int lp_base = 16 * (((D0 >> 3) + (c16 >> 3)) & 3);
            const int jp = c16 & 7;
            const int n16 = rb * 4 + i;
            const size_t fb = (((size_t)b * 8 + n16) * 16 + kc) * 64;
#pragma unroll
            for (int ri = 0; ri < 4; ++ri) {
                const int nlow = quad * 4 + ri;          // n & 15
                size_t o = (fb + nlow + lp_base) * 8 + jp;
                float v = acc[i][j][ri];
                u16 hv = f2bf(v);
                ho_hi[o] = hv;
                ho_lo[o] = f2bf(v - bf2f(hv));
            }
        }
}

// ---------------------------------------------------------------------------
__global__ __launch_bounds__(256)
void score_kernel(const float* __restrict__ prod,   // [L,B,R]
                  const float* __restrict__ lin_w,  // [L,R,O]
                  const float* __restrict__ lin_b,  // [L,O]
                  float* __restrict__ out)          // [B,O]
{
    const int b   = blockIdx.x;
    const int tid = threadIdx.x;

    float acc[O];
#pragma unroll
    for (int o = 0; o < O; ++o) acc[o] = 0.f;

    for (int l = 0; l < L; ++l) {
        const float* pl = prod + ((size_t)l * B + b) * R;
        const float* wl = lin_w + (size_t)l * R * O;
        for (int r = tid; r < R; r += 256) {
            const float p = pl[r];
#pragma unroll
            for (int o = 0; o < O; ++o)
                acc[o] = fmaf(p, wl[r * O + o], acc[o]);
        }
    }

    __shared__ float sb[256];
    for (int o = 0; o < O; ++o) {
        sb[tid] = acc[o];
        __syncthreads();
        for (int off = 128; off > 0; off >>= 1) {
            if (tid < off) sb[tid] += sb[tid + off];
            __syncthreads();
        }
        if (tid == 0) {
            float bias = 0.f;
            for (int l = 0; l < L; ++l) bias += lin_b[l * O + o];
            out[b * O + o] = sb[0] + bias;
        }
        __syncthreads();
    }
}

// ---------------------------------------------------------------------------
extern "C" void kernel_launch(void* const* d_in, const int* in_sizes, int n_in,
                              void* d_out, int out_size, void* d_ws, size_t ws_size,
                              hipStream_t stream) {
    const float* x     = (const float*)d_in[0];   // [B,N,D]
    const int*   edges = (const int*)d_in[1];     // [B,2,E]
    const float* W_cp  = (const float*)d_in[2];   // [L,513,1024]
    const float* lin_w = (const float*)d_in[3];   // [L,R,O]
    const float* lin_b = (const float*)d_in[4];   // [L,O]
    float*       out   = (float*)d_out;           // [B,O]

    char* ws = (char*)d_ws;
    const size_t C_BYTES   = (size_t)B * N * N * 4;        // 16.8 MB
    const size_t CBF_BYTES = (size_t)B * N * N * 2;        // 8.4 MB
    const size_t HH_BYTES  = (size_t)B * N * D * 2;        // 33.6 MB
    const size_t WT_BYTES  = (size_t)L * 1024 * 512 * 2;   // 5.24 MB

    float* C     = (float*)ws;                    ws += C_BYTES;
    u16*   Cbf   = (u16*)ws;                      ws += CBF_BYTES;
    u16*   hiA   = (u16*)ws;                      ws += HH_BYTES;
    u16*   loA   = (u16*)ws;                      ws += HH_BYTES;
    u16*   hiB   = (u16*)ws;                      ws += HH_BYTES;
    u16*   loB   = (u16*)ws;                      ws += HH_BYTES;
    u16*   Wt_hi = (u16*)ws;                      ws += WT_BYTES;
    u16*   Wt_lo = (u16*)ws;                      ws += WT_BYTES;
    float* prod  = (float*)ws;                    // [L,B,R] 5.24 MB

    zero_kernel<<<1024, 256, 0, stream>>>(C, (size_t)B * N * N);
    fill_adj_kernel<<<(B * E + 255) / 256, 256, 0, stream>>>(edges, C);
    diag_kernel<<<(B * N + 255) / 256, 256, 0, stream>>>(C);
    cbf_kernel<<<1024, 256, 0, stream>>>((const float4*)C, (ushort4*)Cbf,
                                         (size_t)B * N * N / 4);
    wt_split_kernel<<<dim3(16, 8, L), 256, 0, stream>>>(W_cp, Wt_hi, Wt_lo);
    split_kernel<<<2048, 256, 0, stream>>>((const float4*)x, hiA, loA,
                                           (size_t)B * N * D / 4);

    // layer 0
    cp_pool_mfma_kernel<<<2048, 256, 0, stream>>>(
        hiA, loA, Wt_hi, Wt_lo, W_cp + (size_t)512 * 1024, prod);

    const u16* phi = hiA; const u16* plo = loA;
    u16* bhi[2] = {hiB, hiA};
    u16* blo[2] = {loB, loA};
    for (int l = 1; l < L; ++l) {
        u16* nhi = bhi[(l - 1) & 1];
        u16* nlo = blo[(l - 1) & 1];
        aggregate_mfma_kernel<<<1024, 256, 0, stream>>>(phi, plo, Cbf, nhi, nlo);
        cp_pool_mfma_kernel<<<2048, 256, 0, stream>>>(
            nhi, nlo,
            Wt_hi + (size_t)l * 1024 * 512, Wt_lo + (size_t)l * 1024 * 512,
            W_cp + ((size_t)l * 513 + 512) * 1024,
            prod + (size_t)l * B * R);
        phi = nhi; plo = nlo;
    }

    score_kernel<<<B, 256, 0, stream>>>(prod, lin_w, lin_b, out);
}